// Round 8
// baseline (235.379 us; speedup 1.0000x reference)
//
#include <hip/hip_runtime.h>
#include <hip/hip_bf16.h>

// Head-axis-softmax SDPA, B=2 S=2048 N=16 D=64, fp32 in/out.
// softmax over HEADS (n) -> local per (b,q,k).
//
// R12: head-split pass1 + pass2 grid revert.
//   - pass1 was ~60us at 512 blocks (2/CU, 2 waves/SIMD, ~200 VGPR,
//     16-head serial chain): latency-bound. Now: block = one (kt,qt) tile,
//     4 waves x 4 heads, LDS [r][wave][lane] reduce (1 barrier), direct
//     packed-fragment bf16 stores. 8192 blocks (32/CU), ~110 VGPR.
//   - pass2: R11's head-major grid REGRESSED vs R9 (77 vs 70us): same-XCD
//     concurrent neighbors must share K/V (x=qt does; x=n shares nothing).
//     Reverted to (qt, n, b). bf16 zr kept.

#define B_ 2
#define S_ 2048
#define N_ 16
#define D_ 64
#define TQ 32
#define TK 32
#define NT 64   // S_/32 tiles per head

typedef __bf16 bf16x4 __attribute__((ext_vector_type(4)));
typedef __bf16 bf16x8 __attribute__((ext_vector_type(8)));
typedef float  f32x16 __attribute__((ext_vector_type(16)));
typedef unsigned int uint32x4 __attribute__((ext_vector_type(4)));

// scale folded into Q at conversion: 1/sqrt(64) * log2(e)
#define QSCALE 0.18033688011112042f

static __device__ __forceinline__ unsigned int cvt_pk_bf16(float a, float b) {
    // dst low16 = bf16(a), high16 = bf16(b)
    unsigned int r;
    asm("v_cvt_pk_bf16_f32 %0, %1, %2" : "=v"(r) : "v"(a), "v"(b));
    return r;
}
static __device__ __forceinline__ void permlane_swap(unsigned int& a, unsigned int& b) {
    // exchanges a's lanes[32:63] with b's lanes[0:31]
    asm("v_permlane32_swap_b32 %0, %1" : "+v"(a), "+v"(b));
}

// ---------------------------------------------------------------------------
// Pre-pass 1: Q,K [b,s,n,d] f32 -> fragment-major packed bf16.
// QP,KP[b][n][s-tile][ks][lane][8]; Q pre-scaled by QSCALE.
// ---------------------------------------------------------------------------
__global__ __launch_bounds__(256) void cvt_qk_pack_kernel(
    const float* __restrict__ Qf, const float* __restrict__ Kf,
    __bf16* __restrict__ QP, __bf16* __restrict__ KP)
{
    const int z = blockIdx.z;                  // 0..2B-1: first B -> Q, rest -> K
    const float* src = (z < B_) ? Qf : Kf;
    __bf16*      dst = (z < B_) ? QP : KP;
    const float scale = (z < B_) ? QSCALE : 1.0f;
    const int b  = (z < B_) ? z : z - B_;
    const int n  = blockIdx.y;
    const int st = blockIdx.x;                 // s-tile 0..63
    const int t  = threadIdx.x;
    const int ks   = t >> 6;
    const int lane = t & 63;
    const int lo   = lane & 31;
    const int hi   = lane >> 5;

    const float* p = &src[(((size_t)b * S_ + st * 32 + lo) * N_ + n) * D_ + ks * 16 + hi * 8];
    const float4 a0 = *(const float4*)p;
    const float4 a1 = *(const float4*)(p + 4);
    bf16x8 o;
    o[0] = (__bf16)(a0.x * scale); o[1] = (__bf16)(a0.y * scale);
    o[2] = (__bf16)(a0.z * scale); o[3] = (__bf16)(a0.w * scale);
    o[4] = (__bf16)(a1.x * scale); o[5] = (__bf16)(a1.y * scale);
    o[6] = (__bf16)(a1.z * scale); o[7] = (__bf16)(a1.w * scale);
    *(bf16x8*)&dst[(((size_t)b * N_ + n) * NT + st) * 2048 + (size_t)t * 8] = o;
}

// ---------------------------------------------------------------------------
// Pre-pass 2: V [b,s,n,d] f32 -> fragment-major packed bf16 (via LDS tile).
// VP[b][n][k-tile][kstep][dt][lane][8].
// ---------------------------------------------------------------------------
__global__ __launch_bounds__(256) void cvt_v_pack_kernel(
    const float* __restrict__ V, __bf16* __restrict__ VP)
{
    __shared__ __bf16 tile[64][68];  // +4 pad breaks bank aliasing
    const int s0 = blockIdx.x * 64;
    const int n  = blockIdx.y;
    const int b  = blockIdx.z;
    const int t  = threadIdx.x;

    {
        const int d4 = (t & 15) * 4;
        const int sr = t >> 4;
        #pragma unroll
        for (int r = 0; r < 4; ++r) {
            const int s = sr + r * 16;
            const float4 v = *(const float4*)&V[(((size_t)b * S_ + s0 + s) * N_ + n) * D_ + d4];
            tile[s][d4 + 0] = (__bf16)v.x;
            tile[s][d4 + 1] = (__bf16)v.y;
            tile[s][d4 + 2] = (__bf16)v.z;
            tile[s][d4 + 3] = (__bf16)v.w;
        }
    }
    __syncthreads();
    {
        const int kstep = t >> 7;        // 0..1
        const int dt    = (t >> 6) & 1;
        const int lane  = t & 63;
        const int lo    = lane & 31;
        const int hi    = lane >> 5;
        #pragma unroll
        for (int kt_sub = 0; kt_sub < 2; ++kt_sub) {
            bf16x8 o;
            #pragma unroll
            for (int j = 0; j < 8; ++j)
                o[j] = tile[kt_sub * 32 + kstep * 16 + hi * 8 + j][dt * 32 + lo];
            const size_t kt = (size_t)(blockIdx.x * 2 + kt_sub);
            *(bf16x8*)&VP[(((size_t)b * N_ + n) * NT + kt) * 2048 + (size_t)t * 8] = o;
        }
    }
}

// ---------------------------------------------------------------------------
// Pass 1 (R12): Zrb packed bf16 = mask ? 1/sum_n exp2(s_n) : NaN.
// Block = one (kt,qt) tile, 4 waves x 4 heads each. Per wave: 4x {8 frag
// loads, 4 swapped MFMA, 16 exp2+add}. Cross-wave reduce via LDS
// red[r][wave][lane] (lane-contiguous -> conflict-free), ONE barrier.
// Wave wv finalizes r = wv*4..wv*4+3: sum 4 partials, rcp, mask, cvt_pk,
// 8B store at packed offset (wv>>1)*512 + lane*8 + (wv&1)*4
// (r=wv*4+i -> kap = i + 8*wv + 4*hi).
// ---------------------------------------------------------------------------
__global__ __launch_bounds__(256, 4) void pass1_z_kernel(
    const __bf16* __restrict__ QP, const __bf16* __restrict__ KP,
    const int* __restrict__ M, __bf16* __restrict__ Zrb)
{
    __shared__ float red[16][4][64];   // 16 KB: [r][wave][lane]
    __shared__ int okf[4];

    const int tid  = threadIdx.x;
    const int wv   = tid >> 6;
    const int lane = tid & 63;
    const int lo   = lane & 31;
    const int hi   = lane >> 5;

    const int kt = blockIdx.x;
    const int qt = blockIdx.y;
    const int b  = blockIdx.z;
    const int k0 = kt * TK;
    const int q0 = qt * TQ;

    const __bf16* Qp = QP + ((size_t)b * N_ * NT + qt) * 2048 + (size_t)lane * 8;
    const __bf16* Kp = KP + ((size_t)b * N_ * NT + kt) * 2048 + (size_t)lane * 8;

    f32x16 z = {};
    #pragma unroll
    for (int i = 0; i < 4; ++i) {
        const int h = wv * 4 + i;
        const __bf16* Qh = Qp + (size_t)h * NT * 2048;
        const __bf16* Kh = Kp + (size_t)h * NT * 2048;
        bf16x8 qf[4], kf[4];
        #pragma unroll
        for (int ks = 0; ks < 4; ++ks) {
            qf[ks] = *(const bf16x8*)(Qh + ks * 512);
            kf[ks] = *(const bf16x8*)(Kh + ks * 512);
        }
        f32x16 s = {};
        #pragma unroll
        for (int ks = 0; ks < 4; ++ks)
            s = __builtin_amdgcn_mfma_f32_32x32x16_bf16(kf[ks], qf[ks], s, 0, 0, 0);
        // s = (q.k)/8 * log2(e) (scale folded into Q); single v_exp_f32 each
        #pragma unroll
        for (int r = 0; r < 16; ++r) z[r] += __builtin_amdgcn_exp2f(s[r]);
    }

    // mask fast-path: block covers the full 32x32 tile with int4 loads.
    const size_t mb = (size_t)b * S_ * S_;
    {
        const int mrow = tid >> 3;          // 0..31
        const int mcol = (tid & 7) * 4;     // 0..28
        const int4 mm = *(const int4*)&M[mb + (size_t)(q0 + mrow) * S_ + k0 + mcol];
        const int ok = (mm.x != 0) & (mm.y != 0) & (mm.z != 0) & (mm.w != 0);
        const int wok = __all(ok);
        if (lane == 0) okf[wv] = wok;
    }

    // deposit partial Z (lane-contiguous per r -> conflict-free)
    #pragma unroll
    for (int r = 0; r < 16; ++r) red[r][wv][lane] = z[r];
    __syncthreads();

    // wave wv finalizes r = wv*4 + i
    float v[4];
    #pragma unroll
    for (int i = 0; i < 4; ++i) {
        const int r = wv * 4 + i;
        const float sum = (red[r][0][lane] + red[r][1][lane])
                        + (red[r][2][lane] + red[r][3][lane]);
        v[i] = __builtin_amdgcn_rcpf(sum);
    }

    if (!(okf[0] & okf[1] & okf[2] & okf[3])) {
        // rare slow path: per-element mask (scattered; correctness only).
        // mask==0: ref softmax over all-(-inf) heads -> NaN weights.
        #pragma unroll
        for (int i = 0; i < 4; ++i) {
            const int kap = i + 8 * wv + 4 * hi;   // kap(r,hi), r = wv*4+i
            if (M[mb + (size_t)(q0 + lo) * S_ + k0 + kap] == 0)
                v[i] = __builtin_nanf("");
        }
    }

    // packed-fragment store: r = g*8+j at offset g*512 + lane*8 + j.
    // our quad: g = wv>>1, j = (wv&1)*4 + i  -> one 8B store.
    const unsigned int u0 = cvt_pk_bf16(v[0], v[1]);
    const unsigned int u1 = cvt_pk_bf16(v[2], v[3]);
    __bf16* Zt = Zrb + (((size_t)b * NT + kt) * NT + qt) * 1024
               + (wv >> 1) * 512 + (size_t)lane * 8 + (wv & 1) * 4;
    *(uint2*)Zt = make_uint2(u0, u1);
}

// ---------------------------------------------------------------------------
// Pass 2: out[b,n,q,:] = sum_k (exp2(s)*zr) V[k,:].  (R9 shape + bf16 zr)
// Block = 256 thr = 4 waves, ONE (q-tile, head, b) per block; wave w sweeps
// k-tiles [w*16, w*16+16). Swapped QK^T; cvt_pk+permlane PV A-frags;
// zr = 2x b128 bf16 packed loads. Grid (qt, n, b): same-XCD concurrent
// neighbors share the head's K/V plane. End: chunked 2x16-row combine.
// ---------------------------------------------------------------------------
__global__ __launch_bounds__(256, 4) void pass2_av_kernel(
    const __bf16* __restrict__ QP, const __bf16* __restrict__ KP,
    const __bf16* __restrict__ VP, const __bf16* __restrict__ Zrb,
    float* __restrict__ O)
{
    __shared__ __align__(16) float obuf[4][16 * D_];    // 16 KB, end combine

    const int tid  = threadIdx.x;
    const int wv   = tid >> 6;
    const int lane = tid & 63;
    const int lo   = lane & 31;
    const int hi   = lane >> 5;

    const int qt = blockIdx.x;
    const int n  = blockIdx.y;
    const int b  = blockIdx.z;
    const int q0 = qt * TQ;

    const __bf16* Qh = QP + (((size_t)b * N_ + n) * NT + qt) * 2048 + (size_t)lane * 8;
    const __bf16* Kh = KP + (((size_t)b * N_ + n) * NT) * 2048 + (size_t)lane * 8;
    const __bf16* Vh = VP + (((size_t)b * N_ + n) * NT) * 2048 + (size_t)lane * 8;
    const __bf16* Zb = Zrb + (size_t)b * NT * NT * 1024 + (size_t)lane * 8;

    // Q fragments (pre-scaled). B-operand of the swapped QK^T.
    bf16x8 qf[4];
    #pragma unroll
    for (int ks = 0; ks < 4; ++ks)
        qf[ks] = *(const bf16x8*)(Qh + ks * 512);

    f32x16 o0 = {};  // out cols d =  0..31 (C layout)
    f32x16 o1 = {};  // out cols d = 32..63

    #pragma unroll 2
    for (int t = 0; t < 16; ++t) {
        const int kt = wv * 16 + t;
        const __bf16* Kt = Kh + (size_t)kt * 2048;
        const __bf16* Vt = Vh + (size_t)kt * 2048;
        const __bf16* Zt = Zb + ((size_t)kt * NT + qt) * 1024;

        // zr (bf16 packed): 2 b128 loads; za covers r=0..7, zb r=8..15.
        const bf16x8 za = *(const bf16x8*)(Zt);
        const bf16x8 zb = *(const bf16x8*)(Zt + 512);

        // K/V frags: lane-contiguous 1KB each.
        bf16x8 kf[4];
        #pragma unroll
        for (int ks = 0; ks < 4; ++ks) kf[ks] = *(const bf16x8*)(Kt + ks * 512);
        bf16x8 vf[2][2];
        #pragma unroll
        for (int kstep = 0; kstep < 2; ++kstep)
            #pragma unroll
            for (int dt = 0; dt < 2; ++dt)
                vf[kstep][dt] = *(const bf16x8*)(Vt + (kstep * 2 + dt) * 512);

        // swapped QK^T: S^T[key=row][q=lo]; lane (lo,hi) holds scores of
        // q = q0+lo at keys kap(r,hi) = (r&3)+8*(r>>2)+4*hi (+kt*32)
        f32x16 s = {};
        #pragma unroll
        for (int ks = 0; ks < 4; ++ks)
            s = __builtin_amdgcn_mfma_f32_32x32x16_bf16(kf[ks], qf[ks], s, 0, 0, 0);

        // w = exp2(s) * zr  (single v_exp_f32; NaN propagates for mask==0)
        float w[16];
        #pragma unroll
        for (int r = 0; r < 8; ++r)  w[r] = __builtin_amdgcn_exp2f(s[r]) * (float)za[r];
        #pragma unroll
        for (int r = 8; r < 16; ++r) w[r] = __builtin_amdgcn_exp2f(s[r]) * (float)zb[r - 8];

        // pack to bf16 + cross-half redistribute -> exact PV A-fragments.
        #pragma unroll
        for (int kstep = 0; kstep < 2; ++kstep) {
            const int e = kstep * 8;
            unsigned int d0 = cvt_pk_bf16(w[e + 0], w[e + 1]);
            unsigned int d1 = cvt_pk_bf16(w[e + 2], w[e + 3]);
            unsigned int d2 = cvt_pk_bf16(w[e + 4], w[e + 5]);
            unsigned int d3 = cvt_pk_bf16(w[e + 6], w[e + 7]);
            permlane_swap(d0, d2);
            permlane_swap(d1, d3);
            uint32x4 u; u[0] = d0; u[1] = d1; u[2] = d2; u[3] = d3;
            const bf16x8 pa = __builtin_bit_cast(bf16x8, u);
            o0 = __builtin_amdgcn_mfma_f32_32x32x16_bf16(pa, vf[kstep][0], o0, 0, 0, 0);
            o1 = __builtin_amdgcn_mfma_f32_32x32x16_bf16(pa, vf[kstep][1], o1, 0, 0, 0);
        }
    }

    // k-split combine, chunked 2 x 16 rows (obuf 16KB, e0=tid*4: 0 conflicts).
    #pragma unroll
    for (int half = 0; half < 2; ++half) {
        if (half) __syncthreads();   // protect obuf reuse
        #pragma unroll
        for (int r8 = 0; r8 < 8; ++r8) {
            const int r  = half * 8 + r8;
            const int lr = (r8 & 3) + 8 * (r8 >> 2) + 4 * hi;  // row - 16*half
            obuf[wv][lr * D_ + lo]      = o0[r];
            obuf[wv][lr * D_ + 32 + lo] = o1[r];
        }
        __syncthreads();
        const int e0 = tid * 4;          // 1024 f32 per half / 256 thr
        float a0 = 0.f, a1 = 0.f, a2 = 0.f, a3 = 0.f;
        #pragma unroll
        for (int w = 0; w < 4; ++w) {
            const float4 x = *(const float4*)&obuf[w][e0];
            a0 += x.x; a1 += x.y; a2 += x.z; a3 += x.w;
        }
        const int q = half * 16 + (e0 >> 6);
        const int d = e0 & 63;
        *(float4*)&O[(((size_t)b * N_ + n) * S_ + q0 + q) * (size_t)D_ + d]
            = make_float4(a0, a1, a2, a3);
    }
}

// ---------------------------------------------------------------------------
// Fallback (fp32 inputs): used only if ws is too small.
// ---------------------------------------------------------------------------
__global__ __launch_bounds__(1024) void sdpa_headsm_kernel(
    const float* __restrict__ Q, const float* __restrict__ K,
    const float* __restrict__ V, const int* __restrict__ M,
    float* __restrict__ O)
{
    __shared__ __align__(16) __bf16 pbuf[N_][TQ][40];

    const int tid  = threadIdx.x;
    const int n    = tid >> 6;
    const int lane = tid & 63;
    const int lo   = lane & 31;
    const int hi   = lane >> 5;

    const int q0 = blockIdx.x * TQ;
    const int b  = blockIdx.y;
    const int kz = blockIdx.z;
    const int FITERS = S_ / TK / 4;

    bf16x8 qf[4];
    {
        const float* qrow = Q + (((size_t)b * S_ + (size_t)(q0 + lo)) * N_ + n) * D_;
        #pragma unroll
        for (int ks = 0; ks < 4; ++ks) {
            const float* p = qrow + ks * 16 + hi * 8;
            float4 a0 = *(const float4*)(p);
            float4 a1 = *(const float4*)(p + 4);
            bf16x8 f;
            f[0] = (__bf16)a0.x; f[1] = (__bf16)a0.y;
            f[2] = (__bf16)a0.z; f[3] = (__bf16)a0.w;
            f[4] = (__bf16)a1.x; f[5] = (__bf16)a1.y;
            f[6] = (__bf16)a1.z; f[7] = (__bf16)a1.w;
            qf[ks] = f;
        }
    }

    f32x16 o0 = {};
    f32x16 o1 = {};

    for (int it = 0; it < FITERS; ++it) {
        const int k0 = (kz * FITERS + it) * TK;

        f32x16 s = {};
        #pragma unroll
        for (int ks = 0; ks < 4; ++ks) {
            const float* krow = K + (((size_t)b * S_ + (size_t)(k0 + lo)) * N_ + n) * D_
                                  + ks * 16 + hi * 8;
            float4 a0 = *(const float4*)(krow);
            float4 a1 = *(const float4*)(krow + 4);
            bf16x8 f;
            f[0] = (__bf16)a0.x; f[1] = (__bf16)a0.y;
            f[2] = (__bf16)a0.z; f[3] = (__bf16)a0.w;
            f[4] = (__bf16)a1.x; f[5] = (__bf16)a1.y;
            f[6] = (__bf16)a1.z; f[7] = (__bf16)a1.w;
            s = __builtin_amdgcn_mfma_f32_32x32x16_bf16(qf[ks], f, s, 0, 0, 0);
        }

        bf16x8 vf[2][2];
        #pragma unroll
        for (int kstep = 0; kstep < 2; ++kstep) {
            #pragma unroll
            for (int dt = 0; dt < 2; ++dt) {
                bf16x8 f;
                #pragma unroll
                for (int j = 0; j < 8; ++j) {
                    const int key = k0 + kstep * 16 + hi * 8 + j;
                    f[j] = (__bf16)V[(((size_t)b * S_ + key) * N_ + n) * D_ + dt * 32 + lo];
                }
                vf[kstep][dt] = f;
            }
        }

        #pragma unroll
        for (int r = 0; r < 16; ++r) {
            const int row = (r & 3) + 8 * (r >> 2) + 4 * hi;
            pbuf[n][row][lo] = (__bf16)__builtin_amdgcn_exp2f(s[r] * QSCALE);
        }

        __syncthreads();

        {
            const int tq = tid >> 5;
            const int tk = tid & 31;
            const int m = M[(size_t)b * S_ * S_ + (size_t)(q0 + tq) * S_ + (k0 + tk)];
            float pv[16];
            float sum = 0.f;
            #pragma unroll
            for (int j = 0; j < 16; ++j) { pv[j] = (float)pbuf[j][tq][tk]; sum += pv[j]; }
            const float rd = m ? (1.0f / sum) : __builtin_nanf("");
            #pragma unroll
            for (int j = 0; j < 16; ++j) pbuf[j][tq][tk] = (__bf16)(pv[j] * rd);
        }

        __syncthreads();

        #pragma unroll
        for (int kstep = 0; kstep < 2; ++kstep) {
            bf16x8 wf = *(const bf16x8*)&pbuf[n][lo][kstep * 16 + hi * 8];
            o0 = __builtin_amdgcn_mfma_f32_32x32x16_bf16(wf, vf[kstep][0], o0, 0, 0, 0);
            o1 = __builtin_amdgcn_mfma_f32_32x32x16_bf16(wf, vf[kstep][1], o1, 0, 0, 0);
        }

        __syncthreads();
    }

    #pragma unroll
    for (int r = 0; r < 16; ++r) {
        const int row = (r & 3) + 8 * (r >> 2) + 4 * hi;
        const size_t base = (((size_t)b * N_ + n) * S_ + (q0 + row)) * (size_t)D_;
        atomicAdd(&O[base + lo],      o0[r]);
        atomicAdd(&O[base + 32 + lo], o1[r]);
    }
}

extern "C" void kernel_launch(void* const* d_in, const int* in_sizes, int n_in,
                              void* d_out, int out_size, void* d_ws, size_t ws_size,
                              hipStream_t stream) {
    const float* Q = (const float*)d_in[0];
    const float* K = (const float*)d_in[1];
    const float* V = (const float*)d_in[2];
    const int*   M = (const int*)d_in[3];
    float* O = (float*)d_out;

    const size_t per  = (size_t)B_ * N_ * NT * 2048;       // 4,194,304 elements
    const size_t zcnt = (size_t)B_ * NT * NT * 1024;       // 8,388,608 elements
    const size_t need = (3 * per + zcnt) * sizeof(__bf16); // 42 MB

    if (ws_size >= need) {
        __bf16* QP = (__bf16*)d_ws;
        __bf16* KP = QP + per;
        __bf16* VP = KP + per;
        __bf16* Zrb = VP + per;
        cvt_qk_pack_kernel<<<dim3(NT, N_, B_ * 2), dim3(256), 0, stream>>>(Q, K, QP, KP);
        cvt_v_pack_kernel<<<dim3(S_ / 64, N_, B_), dim3(256), 0, stream>>>(V, VP);
        pass1_z_kernel<<<dim3(NT, NT, B_), dim3(256), 0, stream>>>(QP, KP, M, Zrb);
        pass2_av_kernel<<<dim3(NT, N_, B_), dim3(256), 0, stream>>>(QP, KP, VP, Zrb, O);
    } else {
        hipMemsetAsync(d_out, 0, (size_t)out_size * sizeof(float), stream);
        sdpa_headsm_kernel<<<dim3(S_ / TQ, B_, 4), dim3(1024), 0, stream>>>(Q, K, V, M, O);
    }
}

// Round 10
// 212.708 us; speedup vs baseline: 1.1066x; 1.1066x over previous
//
#include <hip/hip_runtime.h>
#include <hip/hip_bf16.h>

// Head-axis-softmax SDPA, B=2 S=2048 N=16 D=64, fp32 in/out.
// softmax over HEADS (n) -> local per (b,q,k).
//
// R14: proven-best pair, no experiments.
//   - pass1: R11's 2ktx2qt wave blocking (fastest measured) storing f32
//     1/Z (rcp) in the R9-verified packed fragment layout.
//   - pass2: R9's exact kernel (proven 70us): f32 zr multiply, grid
//     (qt,n,b), chunked conflict-free combine.
//   R13's lz=-log2(Z) MFMA-seed FAILED correctness (absmax 6.06) -- the
//   log/seed value path is the only unverified component; reverted.

#define B_ 2
#define S_ 2048
#define N_ 16
#define D_ 64
#define TQ 32
#define TK 32
#define NT 64   // S_/32 tiles per head

typedef __bf16 bf16x4 __attribute__((ext_vector_type(4)));
typedef __bf16 bf16x8 __attribute__((ext_vector_type(8)));
typedef float  f32x16 __attribute__((ext_vector_type(16)));
typedef unsigned int uint32x4 __attribute__((ext_vector_type(4)));

// scale folded into Q at conversion: 1/sqrt(64) * log2(e)
#define QSCALE 0.18033688011112042f

static __device__ __forceinline__ unsigned int cvt_pk_bf16(float a, float b) {
    // dst low16 = bf16(a), high16 = bf16(b)
    unsigned int r;
    asm("v_cvt_pk_bf16_f32 %0, %1, %2" : "=v"(r) : "v"(a), "v"(b));
    return r;
}
static __device__ __forceinline__ void permlane_swap(unsigned int& a, unsigned int& b) {
    // exchanges a's lanes[32:63] with b's lanes[0:31]
    asm("v_permlane32_swap_b32 %0, %1" : "+v"(a), "+v"(b));
}

// ---------------------------------------------------------------------------
// Pre-pass 1: Q,K [b,s,n,d] f32 -> fragment-major packed bf16.
// QP,KP[b][n][s-tile][ks][lane][8]; Q pre-scaled by QSCALE.
// ---------------------------------------------------------------------------
__global__ __launch_bounds__(256) void cvt_qk_pack_kernel(
    const float* __restrict__ Qf, const float* __restrict__ Kf,
    __bf16* __restrict__ QP, __bf16* __restrict__ KP)
{
    const int z = blockIdx.z;                  // 0..2B-1: first B -> Q, rest -> K
    const float* src = (z < B_) ? Qf : Kf;
    __bf16*      dst = (z < B_) ? QP : KP;
    const float scale = (z < B_) ? QSCALE : 1.0f;
    const int b  = (z < B_) ? z : z - B_;
    const int n  = blockIdx.y;
    const int st = blockIdx.x;                 // s-tile 0..63
    const int t  = threadIdx.x;
    const int ks   = t >> 6;
    const int lane = t & 63;
    const int lo   = lane & 31;
    const int hi   = lane >> 5;

    const float* p = &src[(((size_t)b * S_ + st * 32 + lo) * N_ + n) * D_ + ks * 16 + hi * 8];
    const float4 a0 = *(const float4*)p;
    const float4 a1 = *(const float4*)(p + 4);
    bf16x8 o;
    o[0] = (__bf16)(a0.x * scale); o[1] = (__bf16)(a0.y * scale);
    o[2] = (__bf16)(a0.z * scale); o[3] = (__bf16)(a0.w * scale);
    o[4] = (__bf16)(a1.x * scale); o[5] = (__bf16)(a1.y * scale);
    o[6] = (__bf16)(a1.z * scale); o[7] = (__bf16)(a1.w * scale);
    *(bf16x8*)&dst[(((size_t)b * N_ + n) * NT + st) * 2048 + (size_t)t * 8] = o;
}

// ---------------------------------------------------------------------------
// Pre-pass 2: V [b,s,n,d] f32 -> fragment-major packed bf16 (via LDS tile).
// VP[b][n][k-tile][kstep][dt][lane][8].
// ---------------------------------------------------------------------------
__global__ __launch_bounds__(256) void cvt_v_pack_kernel(
    const float* __restrict__ V, __bf16* __restrict__ VP)
{
    __shared__ __bf16 tile[64][68];  // +4 pad breaks bank aliasing
    const int s0 = blockIdx.x * 64;
    const int n  = blockIdx.y;
    const int b  = blockIdx.z;
    const int t  = threadIdx.x;

    {
        const int d4 = (t & 15) * 4;
        const int sr = t >> 4;
        #pragma unroll
        for (int r = 0; r < 4; ++r) {
            const int s = sr + r * 16;
            const float4 v = *(const float4*)&V[(((size_t)b * S_ + s0 + s) * N_ + n) * D_ + d4];
            tile[s][d4 + 0] = (__bf16)v.x;
            tile[s][d4 + 1] = (__bf16)v.y;
            tile[s][d4 + 2] = (__bf16)v.z;
            tile[s][d4 + 3] = (__bf16)v.w;
        }
    }
    __syncthreads();
    {
        const int kstep = t >> 7;        // 0..1
        const int dt    = (t >> 6) & 1;
        const int lane  = t & 63;
        const int lo    = lane & 31;
        const int hi    = lane >> 5;
        #pragma unroll
        for (int kt_sub = 0; kt_sub < 2; ++kt_sub) {
            bf16x8 o;
            #pragma unroll
            for (int j = 0; j < 8; ++j)
                o[j] = tile[kt_sub * 32 + kstep * 16 + hi * 8 + j][dt * 32 + lo];
            const size_t kt = (size_t)(blockIdx.x * 2 + kt_sub);
            *(bf16x8*)&VP[(((size_t)b * N_ + n) * NT + kt) * 2048 + (size_t)t * 8] = o;
        }
    }
}

// ---------------------------------------------------------------------------
// Pass 1 (R11 structure, f32 rcp store): Zr packed f32 = mask ? 1/Z : NaN,
// in pass2's fragment layout: Zr[((b*NT+kt)*NT+qt)*1024 + c*256 + lane*4 + j]
// holds 1/Z at (q = qt*32+(lane&31), k = kt*32 + kap(4c+j, lane>>5)),
// kap(r,hi) = (r&3)+8*(r>>2)+4*hi.
// Block = 4 waves; wave wv: k-tiles ktA=(bx*4+wv)*2, ktA+1;
// q-tiles qt0=by*2, qt0+1. SWAPPED QK^T (mfma(K,Q)): C-layout == packed order.
// 2x2 blocking: per head 16 frag loads -> 16 MFMA (Q and K both amortized 2x).
// ---------------------------------------------------------------------------
__global__ __launch_bounds__(256, 2) void pass1_z_kernel(
    const __bf16* __restrict__ QP, const __bf16* __restrict__ KP,
    const int* __restrict__ M, float* __restrict__ Zr)
{
    const int tid  = threadIdx.x;
    const int wv   = tid >> 6;
    const int lane = tid & 63;
    const int lo   = lane & 31;
    const int hi   = lane >> 5;

    const int ktA = (blockIdx.x * 4 + wv) * 2;
    const int qt0 = blockIdx.y * 2;
    const int b   = blockIdx.z;
    const int k0A = ktA * TK;
    const int q0  = qt0 * TQ;

    const __bf16* Qp = QP + ((size_t)b * N_ * NT + qt0) * 2048 + (size_t)lane * 8;
    const __bf16* Kp = KP + ((size_t)b * N_ * NT + ktA) * 2048 + (size_t)lane * 8;

    f32x16 zAA = {}, zAB = {}, zBA = {}, zBB = {};   // z[kt][qt]
    for (int h = 0; h < N_; ++h) {
        const __bf16* Qh = Qp + (size_t)h * NT * 2048;
        const __bf16* Kh = Kp + (size_t)h * NT * 2048;
        bf16x8 q0f[4], q1f[4], ka[4], kb[4];
        #pragma unroll
        for (int ks = 0; ks < 4; ++ks) {
            q0f[ks] = *(const bf16x8*)(Qh + ks * 512);
            q1f[ks] = *(const bf16x8*)(Qh + 2048 + ks * 512);
            ka[ks]  = *(const bf16x8*)(Kh + ks * 512);
            kb[ks]  = *(const bf16x8*)(Kh + 2048 + ks * 512);
        }
        f32x16 s;
        s = (f32x16){};
        #pragma unroll
        for (int ks = 0; ks < 4; ++ks) s = __builtin_amdgcn_mfma_f32_32x32x16_bf16(ka[ks], q0f[ks], s, 0, 0, 0);
        #pragma unroll
        for (int r = 0; r < 16; ++r) zAA[r] += __builtin_amdgcn_exp2f(s[r]);
        s = (f32x16){};
        #pragma unroll
        for (int ks = 0; ks < 4; ++ks) s = __builtin_amdgcn_mfma_f32_32x32x16_bf16(ka[ks], q1f[ks], s, 0, 0, 0);
        #pragma unroll
        for (int r = 0; r < 16; ++r) zAB[r] += __builtin_amdgcn_exp2f(s[r]);
        s = (f32x16){};
        #pragma unroll
        for (int ks = 0; ks < 4; ++ks) s = __builtin_amdgcn_mfma_f32_32x32x16_bf16(kb[ks], q0f[ks], s, 0, 0, 0);
        #pragma unroll
        for (int r = 0; r < 16; ++r) zBA[r] += __builtin_amdgcn_exp2f(s[r]);
        s = (f32x16){};
        #pragma unroll
        for (int ks = 0; ks < 4; ++ks) s = __builtin_amdgcn_mfma_f32_32x32x16_bf16(kb[ks], q1f[ks], s, 0, 0, 0);
        #pragma unroll
        for (int r = 0; r < 16; ++r) zBB[r] += __builtin_amdgcn_exp2f(s[r]);
    }

    // mask fast-path: AND-reduce rows q0..q0+63 x cols k0A..k0A+63 (int4).
    const size_t mb = (size_t)b * S_ * S_;
    int ok = 1;
    #pragma unroll
    for (int r = 0; r < 16; ++r) {
        const int4 mm = *(const int4*)&M[mb + (size_t)(q0 + 4 * r + (lane >> 4)) * S_
                                         + k0A + (lane & 15) * 4];
        ok &= (mm.x != 0) & (mm.y != 0) & (mm.z != 0) & (mm.w != 0);
    }

    float vAA[16], vAB[16], vBA[16], vBB[16];
    #pragma unroll
    for (int r = 0; r < 16; ++r) {
        vAA[r] = __builtin_amdgcn_rcpf(zAA[r]);
        vAB[r] = __builtin_amdgcn_rcpf(zAB[r]);
        vBA[r] = __builtin_amdgcn_rcpf(zBA[r]);
        vBB[r] = __builtin_amdgcn_rcpf(zBB[r]);
    }

    if (!__all(ok)) {
        // rare slow path: per-element mask (scattered; correctness only).
        // mask==0: ref softmax over all-(-inf) heads -> NaN weights.
        #pragma unroll
        for (int r = 0; r < 16; ++r) {
            const int kap = (r & 3) + 8 * (r >> 2) + 4 * hi;
            const size_t rowA = mb + (size_t)(q0 + lo) * S_;
            const size_t rowB = mb + (size_t)(q0 + 32 + lo) * S_;
            if (M[rowA + k0A + kap] == 0)      vAA[r] = __builtin_nanf("");
            if (M[rowB + k0A + kap] == 0)      vAB[r] = __builtin_nanf("");
            if (M[rowA + k0A + 32 + kap] == 0) vBA[r] = __builtin_nanf("");
            if (M[rowB + k0A + 32 + kap] == 0) vBB[r] = __builtin_nanf("");
        }
    }

    auto store_tile = [&](const float (&v)[16], int kt_, int qt_) {
        float* Zt = Zr + (((size_t)b * NT + kt_) * NT + qt_) * 1024 + (size_t)lane * 4;
        #pragma unroll
        for (int c = 0; c < 4; ++c)
            *(float4*)(Zt + c * 256) = make_float4(v[4*c], v[4*c+1], v[4*c+2], v[4*c+3]);
    };
    store_tile(vAA, ktA,     qt0);
    store_tile(vAB, ktA,     qt0 + 1);
    store_tile(vBA, ktA + 1, qt0);
    store_tile(vBB, ktA + 1, qt0 + 1);
}

// ---------------------------------------------------------------------------
// Pass 2 (R9 exact): out[b,n,q,:] = sum_k (exp2(s)*zr) V[k,:].
// Block = 256 thr = 4 waves, ONE (q-tile, head, b) per block; wave w sweeps
// k-tiles [w*16, w*16+16). Swapped QK^T; cvt_pk+permlane PV A-frags;
// zr = 4x f32 b128 packed loads, multiply after exp2. Grid (qt, n, b):
// same-XCD concurrent neighbors share the head's K/V plane.
// End: chunked 2x16-row combine (16KB obuf, e0=tid*4: 0 conflicts).
// ---------------------------------------------------------------------------
__global__ __launch_bounds__(256, 4) void pass2_av_kernel(
    const __bf16* __restrict__ QP, const __bf16* __restrict__ KP,
    const __bf16* __restrict__ VP, const float* __restrict__ Zr,
    float* __restrict__ O)
{
    __shared__ __align__(16) float obuf[4][16 * D_];    // 16 KB, end combine

    const int tid  = threadIdx.x;
    const int wv   = tid >> 6;
    const int lane = tid & 63;
    const int lo   = lane & 31;
    const int hi   = lane >> 5;

    const int qt = blockIdx.x;
    const int n  = blockIdx.y;
    const int b  = blockIdx.z;
    const int q0 = qt * TQ;

    const __bf16* Qh = QP + (((size_t)b * N_ + n) * NT + qt) * 2048 + (size_t)lane * 8;
    const __bf16* Kh = KP + (((size_t)b * N_ + n) * NT) * 2048 + (size_t)lane * 8;
    const __bf16* Vh = VP + (((size_t)b * N_ + n) * NT) * 2048 + (size_t)lane * 8;
    const float*  Zb = Zr + (size_t)b * NT * NT * 1024 + (size_t)lane * 4;

    // Q fragments (pre-scaled). B-operand of the swapped QK^T.
    bf16x8 qf[4];
    #pragma unroll
    for (int ks = 0; ks < 4; ++ks)
        qf[ks] = *(const bf16x8*)(Qh + ks * 512);

    f32x16 o0 = {};  // out cols d =  0..31 (C layout)
    f32x16 o1 = {};  // out cols d = 32..63

    #pragma unroll 2
    for (int t = 0; t < 16; ++t) {
        const int kt = wv * 16 + t;
        const __bf16* Kt = Kh + (size_t)kt * 2048;
        const __bf16* Vt = Vh + (size_t)kt * 2048;
        const float*  Zt = Zb + ((size_t)kt * NT + qt) * 1024;

        // zr: 4 coalesced b128 loads from packed layout; zr[4c+j] = chunk c, j.
        float4 z0 = *(const float4*)(Zt);
        float4 z1 = *(const float4*)(Zt + 256);
        float4 z2 = *(const float4*)(Zt + 512);
        float4 z3 = *(const float4*)(Zt + 768);
        float zr[16] = { z0.x, z0.y, z0.z, z0.w,  z1.x, z1.y, z1.z, z1.w,
                         z2.x, z2.y, z2.z, z2.w,  z3.x, z3.y, z3.z, z3.w };

        // K/V frags: lane-contiguous 1KB each.
        bf16x8 kf[4];
        #pragma unroll
        for (int ks = 0; ks < 4; ++ks) kf[ks] = *(const bf16x8*)(Kt + ks * 512);
        bf16x8 vf[2][2];
        #pragma unroll
        for (int kstep = 0; kstep < 2; ++kstep)
            #pragma unroll
            for (int dt = 0; dt < 2; ++dt)
                vf[kstep][dt] = *(const bf16x8*)(Vt + (kstep * 2 + dt) * 512);

        // swapped QK^T: S^T[key=row][q=lo]; lane (lo,hi) holds scores of
        // q = q0+lo at keys kap(r,hi) = (r&3)+8*(r>>2)+4*hi (+kt*32)
        f32x16 s = {};
        #pragma unroll
        for (int ks = 0; ks < 4; ++ks)
            s = __builtin_amdgcn_mfma_f32_32x32x16_bf16(kf[ks], qf[ks], s, 0, 0, 0);

        // w = exp2(s) * zr  (single v_exp_f32; NaN propagates for mask==0)
        float w[16];
        #pragma unroll
        for (int r = 0; r < 16; ++r) w[r] = __builtin_amdgcn_exp2f(s[r]) * zr[r];

        // pack to bf16 + cross-half redistribute -> exact PV A-fragments.
        #pragma unroll
        for (int kstep = 0; kstep < 2; ++kstep) {
            const int e = kstep * 8;
            unsigned int d0 = cvt_pk_bf16(w[e + 0], w[e + 1]);
            unsigned int d1 = cvt_pk_bf16(w[e + 2], w[e + 3]);
            unsigned int d2 = cvt_pk_bf16(w[e + 4], w[e + 5]);
            unsigned int d3 = cvt_pk_bf16(w[e + 6], w[e + 7]);
            permlane_swap(d0, d2);
            permlane_swap(d1, d3);
            uint32x4 u; u[0] = d0; u[1] = d1; u[2] = d2; u[3] = d3;
            const bf16x8 pa = __builtin_bit_cast(bf16x8, u);
            o0 = __builtin_amdgcn_mfma_f32_32x32x16_bf16(pa, vf[kstep][0], o0, 0, 0, 0);
            o1 = __builtin_amdgcn_mfma_f32_32x32x16_bf16(pa, vf[kstep][1], o1, 0, 0, 0);
        }
    }

    // k-split combine, chunked 2 x 16 rows (obuf 16KB, e0=tid*4: 0 conflicts).
    #pragma unroll
    for (int half = 0; half < 2; ++half) {
        if (half) __syncthreads();   // protect obuf reuse
        #pragma unroll
        for (int r8 = 0; r8 < 8; ++r8) {
            const int r  = half * 8 + r8;
            const int lr = (r8 & 3) + 8 * (r8 >> 2) + 4 * hi;  // row - 16*half
            obuf[wv][lr * D_ + lo]      = o0[r];
            obuf[wv][lr * D_ + 32 + lo] = o1[r];
        }
        __syncthreads();
        const int e0 = tid * 4;          // 1024 f32 per half / 256 thr
        float a0 = 0.f, a1 = 0.f, a2 = 0.f, a3 = 0.f;
        #pragma unroll
        for (int w = 0; w < 4; ++w) {
            const float4 x = *(const float4*)&obuf[w][e0];
            a0 += x.x; a1 += x.y; a2 += x.z; a3 += x.w;
        }
        const int q = half * 16 + (e0 >> 6);
        const int d = e0 & 63;
        *(float4*)&O[(((size_t)b * N_ + n) * S_ + q0 + q) * (size_t)D_ + d]
            = make_float4(a0, a1, a2, a3);
    }
}

// ---------------------------------------------------------------------------
// Fallback (fp32 inputs): used only if ws is too small.
// ---------------------------------------------------------------------------
__global__ __launch_bounds__(1024) void sdpa_headsm_kernel(
    const float* __restrict__ Q, const float* __restrict__ K,
    const float* __restrict__ V, const int* __restrict__ M,
    float* __restrict__ O)
{
    __shared__ __align__(16) __bf16 pbuf[N_][TQ][40];

    const int tid  = threadIdx.x;
    const int n    = tid >> 6;
    const int lane = tid & 63;
    const int lo   = lane & 31;
    const int hi   = lane >> 5;

    const int q0 = blockIdx.x * TQ;
    const int b  = blockIdx.y;
    const int kz = blockIdx.z;
    const int FITERS = S_ / TK / 4;

    bf16x8 qf[4];
    {
        const float* qrow = Q + (((size_t)b * S_ + (size_t)(q0 + lo)) * N_ + n) * D_;
        #pragma unroll
        for (int ks = 0; ks < 4; ++ks) {
            const float* p = qrow + ks * 16 + hi * 8;
            float4 a0 = *(const float4*)(p);
            float4 a1 = *(const float4*)(p + 4);
            bf16x8 f;
            f[0] = (__bf16)a0.x; f[1] = (__bf16)a0.y;
            f[2] = (__bf16)a0.z; f[3] = (__bf16)a0.w;
            f[4] = (__bf16)a1.x; f[5] = (__bf16)a1.y;
            f[6] = (__bf16)a1.z; f[7] = (__bf16)a1.w;
            qf[ks] = f;
        }
    }

    f32x16 o0 = {};
    f32x16 o1 = {};

    for (int it = 0; it < FITERS; ++it) {
        const int k0 = (kz * FITERS + it) * TK;

        f32x16 s = {};
        #pragma unroll
        for (int ks = 0; ks < 4; ++ks) {
            const float* krow = K + (((size_t)b * S_ + (size_t)(k0 + lo)) * N_ + n) * D_
                                  + ks * 16 + hi * 8;
            float4 a0 = *(const float4*)(krow);
            float4 a1 = *(const float4*)(krow + 4);
            bf16x8 f;
            f[0] = (__bf16)a0.x; f[1] = (__bf16)a0.y;
            f[2] = (__bf16)a0.z; f[3] = (__bf16)a0.w;
            f[4] = (__bf16)a1.x; f[5] = (__bf16)a1.y;
            f[6] = (__bf16)a1.z; f[7] = (__bf16)a1.w;
            s = __builtin_amdgcn_mfma_f32_32x32x16_bf16(qf[ks], f, s, 0, 0, 0);
        }

        bf16x8 vf[2][2];
        #pragma unroll
        for (int kstep = 0; kstep < 2; ++kstep) {
            #pragma unroll
            for (int dt = 0; dt < 2; ++dt) {
                bf16x8 f;
                #pragma unroll
                for (int j = 0; j < 8; ++j) {
                    const int key = k0 + kstep * 16 + hi * 8 + j;
                    f[j] = (__bf16)V[(((size_t)b * S_ + key) * N_ + n) * D_ + dt * 32 + lo];
                }
                vf[kstep][dt] = f;
            }
        }

        #pragma unroll
        for (int r = 0; r < 16; ++r) {
            const int row = (r & 3) + 8 * (r >> 2) + 4 * hi;
            pbuf[n][row][lo] = (__bf16)__builtin_amdgcn_exp2f(s[r] * QSCALE);
        }

        __syncthreads();

        {
            const int tq = tid >> 5;
            const int tk = tid & 31;
            const int m = M[(size_t)b * S_ * S_ + (size_t)(q0 + tq) * S_ + (k0 + tk)];
            float pv[16];
            float sum = 0.f;
            #pragma unroll
            for (int j = 0; j < 16; ++j) { pv[j] = (float)pbuf[j][tq][tk]; sum += pv[j]; }
            const float rd = m ? (1.0f / sum) : __builtin_nanf("");
            #pragma unroll
            for (int j = 0; j < 16; ++j) pbuf[j][tq][tk] = (__bf16)(pv[j] * rd);
        }

        __syncthreads();

        #pragma unroll
        for (int kstep = 0; kstep < 2; ++kstep) {
            bf16x8 wf = *(const bf16x8*)&pbuf[n][lo][kstep * 16 + hi * 8];
            o0 = __builtin_amdgcn_mfma_f32_32x32x16_bf16(wf, vf[kstep][0], o0, 0, 0, 0);
            o1 = __builtin_amdgcn_mfma_f32_32x32x16_bf16(wf, vf[kstep][1], o1, 0, 0, 0);
        }

        __syncthreads();
    }

    #pragma unroll
    for (int r = 0; r < 16; ++r) {
        const int row = (r & 3) + 8 * (r >> 2) + 4 * hi;
        const size_t base = (((size_t)b * N_ + n) * S_ + (q0 + row)) * (size_t)D_;
        atomicAdd(&O[base + lo],      o0[r]);
        atomicAdd(&O[base + 32 + lo], o1[r]);
    }
}

extern "C" void kernel_launch(void* const* d_in, const int* in_sizes, int n_in,
                              void* d_out, int out_size, void* d_ws, size_t ws_size,
                              hipStream_t stream) {
    const float* Q = (const float*)d_in[0];
    const float* K = (const float*)d_in[1];
    const float* V = (const float*)d_in[2];
    const int*   M = (const int*)d_in[3];
    float* O = (float*)d_out;

    const size_t per  = (size_t)B_ * N_ * NT * 2048;       // 4,194,304 elements
    const size_t zcnt = (size_t)B_ * NT * NT * 1024;       // 8,388,608 elements
    const size_t need = 3 * per * sizeof(__bf16) + zcnt * sizeof(float);  // 56 MB

    if (ws_size >= need) {
        __bf16* QP = (__bf16*)d_ws;
        __bf16* KP = QP + per;
        __bf16* VP = KP + per;
        float*  Zr = (float*)(VP + per);
        cvt_qk_pack_kernel<<<dim3(NT, N_, B_ * 2), dim3(256), 0, stream>>>(Q, K, QP, KP);
        cvt_v_pack_kernel<<<dim3(S_ / 64, N_, B_), dim3(256), 0, stream>>>(V, VP);
        pass1_z_kernel<<<dim3(NT / 8, NT / 2, B_), dim3(256), 0, stream>>>(QP, KP, M, Zr);
        pass2_av_kernel<<<dim3(NT, N_, B_), dim3(256), 0, stream>>>(QP, KP, VP, Zr, O);
    } else {
        hipMemsetAsync(d_out, 0, (size_t)out_size * sizeof(float), stream);
        sdpa_headsm_kernel<<<dim3(S_ / TQ, B_, 4), dim3(1024), 0, stream>>>(Q, K, V, M, O);
    }
}

// Round 11
// 209.481 us; speedup vs baseline: 1.1236x; 1.0154x over previous
//
#include <hip/hip_runtime.h>
#include <hip/hip_bf16.h>

// Head-axis-softmax SDPA, B=2 S=2048 N=16 D=64, fp32 in/out.
// softmax over HEADS (n) -> local per (b,q,k).
//
// R15: pass2 latency fix + merged cvt + pass1 unroll.
//   - pass2: R14's loop issued zr,vf,kf but consumed kf FIRST -> the wait
//     for kf drained all 12 loads (vmcnt is issue-ordered), exposing a full
//     L2 round-trip per k-tile. Now kf is double-buffered across iterations
//     (tile t+1's K loads issue under tile t's compute) and in-iteration
//     order is zr -> vf -> kf_next, so zr waits at vmcnt(8), vf at vmcnt(4).
//     __launch_bounds__(256,3) (~170 VGPR cap) to avoid spills.
//   - cvt_qk + cvt_v merged into one kernel (one fewer launch gap).
//   - pass1: #pragma unroll 2 on head loop (next head's loads issue under
//     current head's exp chain).

#define B_ 2
#define S_ 2048
#define N_ 16
#define D_ 64
#define TQ 32
#define TK 32
#define NT 64   // S_/32 tiles per head

typedef __bf16 bf16x4 __attribute__((ext_vector_type(4)));
typedef __bf16 bf16x8 __attribute__((ext_vector_type(8)));
typedef float  f32x16 __attribute__((ext_vector_type(16)));
typedef unsigned int uint32x4 __attribute__((ext_vector_type(4)));

// scale folded into Q at conversion: 1/sqrt(64) * log2(e)
#define QSCALE 0.18033688011112042f

static __device__ __forceinline__ unsigned int cvt_pk_bf16(float a, float b) {
    // dst low16 = bf16(a), high16 = bf16(b)
    unsigned int r;
    asm("v_cvt_pk_bf16_f32 %0, %1, %2" : "=v"(r) : "v"(a), "v"(b));
    return r;
}
static __device__ __forceinline__ void permlane_swap(unsigned int& a, unsigned int& b) {
    // exchanges a's lanes[32:63] with b's lanes[0:31]
    asm("v_permlane32_swap_b32 %0, %1" : "+v"(a), "+v"(b));
}

// ---------------------------------------------------------------------------
// Merged pre-pass: Q,K,V [b,s,n,d] f32 -> fragment-major packed bf16.
//   z in [0,2B): Q/K path -> QP,KP[b][n][s-tile][ks][lane][8], Q pre-scaled.
//   z in [2B,3B): V path (LDS d<->s transpose) -> VP[b][n][kt][kstep][dt][lane][8];
//                 only blockIdx.x < S_/64 active.
// ---------------------------------------------------------------------------
__global__ __launch_bounds__(256) void cvt_pack_kernel(
    const float* __restrict__ Qf, const float* __restrict__ Kf,
    const float* __restrict__ Vf,
    __bf16* __restrict__ QP, __bf16* __restrict__ KP, __bf16* __restrict__ VP)
{
    __shared__ __bf16 tile[64][68];  // V path only; +4 pad breaks bank aliasing
    const int z = blockIdx.z;
    const int t = threadIdx.x;

    if (z < 2 * B_) {
        // ---- Q/K fragment pack ----
        const float* src = (z < B_) ? Qf : Kf;
        __bf16*      dst = (z < B_) ? QP : KP;
        const float scale = (z < B_) ? QSCALE : 1.0f;
        const int b  = (z < B_) ? z : z - B_;
        const int n  = blockIdx.y;
        const int st = blockIdx.x;                 // s-tile 0..63
        const int ks   = t >> 6;
        const int lane = t & 63;
        const int lo   = lane & 31;
        const int hi   = lane >> 5;

        const float* p = &src[(((size_t)b * S_ + st * 32 + lo) * N_ + n) * D_ + ks * 16 + hi * 8];
        const float4 a0 = *(const float4*)p;
        const float4 a1 = *(const float4*)(p + 4);
        bf16x8 o;
        o[0] = (__bf16)(a0.x * scale); o[1] = (__bf16)(a0.y * scale);
        o[2] = (__bf16)(a0.z * scale); o[3] = (__bf16)(a0.w * scale);
        o[4] = (__bf16)(a1.x * scale); o[5] = (__bf16)(a1.y * scale);
        o[6] = (__bf16)(a1.z * scale); o[7] = (__bf16)(a1.w * scale);
        *(bf16x8*)&dst[(((size_t)b * N_ + n) * NT + st) * 2048 + (size_t)t * 8] = o;
    } else {
        // ---- V transpose pack ----
        if (blockIdx.x >= S_ / 64) return;
        const int b  = z - 2 * B_;
        const int s0 = blockIdx.x * 64;
        const int n  = blockIdx.y;
        {
            const int d4 = (t & 15) * 4;
            const int sr = t >> 4;
            #pragma unroll
            for (int r = 0; r < 4; ++r) {
                const int s = sr + r * 16;
                const float4 v = *(const float4*)&Vf[(((size_t)b * S_ + s0 + s) * N_ + n) * D_ + d4];
                tile[s][d4 + 0] = (__bf16)v.x;
                tile[s][d4 + 1] = (__bf16)v.y;
                tile[s][d4 + 2] = (__bf16)v.z;
                tile[s][d4 + 3] = (__bf16)v.w;
            }
        }
        __syncthreads();
        {
            const int kstep = t >> 7;        // 0..1
            const int dt    = (t >> 6) & 1;
            const int lane  = t & 63;
            const int lo    = lane & 31;
            const int hi    = lane >> 5;
            #pragma unroll
            for (int kt_sub = 0; kt_sub < 2; ++kt_sub) {
                bf16x8 o;
                #pragma unroll
                for (int j = 0; j < 8; ++j)
                    o[j] = tile[kt_sub * 32 + kstep * 16 + hi * 8 + j][dt * 32 + lo];
                const size_t kt = (size_t)(blockIdx.x * 2 + kt_sub);
                *(bf16x8*)&VP[(((size_t)b * N_ + n) * NT + kt) * 2048 + (size_t)t * 8] = o;
            }
        }
    }
}

// ---------------------------------------------------------------------------
// Pass 1 (R11 structure, f32 rcp store, head loop unroll 2):
// Zr packed f32 = mask ? 1/Z : NaN, in pass2's fragment layout:
// Zr[((b*NT+kt)*NT+qt)*1024 + c*256 + lane*4 + j] holds 1/Z at
// (q = qt*32+(lane&31), k = kt*32 + kap(4c+j, lane>>5)),
// kap(r,hi) = (r&3)+8*(r>>2)+4*hi.
// Block = 4 waves; wave wv: k-tiles ktA=(bx*4+wv)*2, ktA+1;
// q-tiles qt0=by*2, qt0+1. SWAPPED QK^T (mfma(K,Q)): C-layout == packed order.
// ---------------------------------------------------------------------------
__global__ __launch_bounds__(256, 2) void pass1_z_kernel(
    const __bf16* __restrict__ QP, const __bf16* __restrict__ KP,
    const int* __restrict__ M, float* __restrict__ Zr)
{
    const int tid  = threadIdx.x;
    const int wv   = tid >> 6;
    const int lane = tid & 63;
    const int lo   = lane & 31;
    const int hi   = lane >> 5;

    const int ktA = (blockIdx.x * 4 + wv) * 2;
    const int qt0 = blockIdx.y * 2;
    const int b   = blockIdx.z;
    const int k0A = ktA * TK;
    const int q0  = qt0 * TQ;

    const __bf16* Qp = QP + ((size_t)b * N_ * NT + qt0) * 2048 + (size_t)lane * 8;
    const __bf16* Kp = KP + ((size_t)b * N_ * NT + ktA) * 2048 + (size_t)lane * 8;

    f32x16 zAA = {}, zAB = {}, zBA = {}, zBB = {};   // z[kt][qt]
    #pragma unroll 2
    for (int h = 0; h < N_; ++h) {
        const __bf16* Qh = Qp + (size_t)h * NT * 2048;
        const __bf16* Kh = Kp + (size_t)h * NT * 2048;
        bf16x8 q0f[4], q1f[4], ka[4], kb[4];
        #pragma unroll
        for (int ks = 0; ks < 4; ++ks) {
            q0f[ks] = *(const bf16x8*)(Qh + ks * 512);
            q1f[ks] = *(const bf16x8*)(Qh + 2048 + ks * 512);
            ka[ks]  = *(const bf16x8*)(Kh + ks * 512);
            kb[ks]  = *(const bf16x8*)(Kh + 2048 + ks * 512);
        }
        f32x16 s;
        s = (f32x16){};
        #pragma unroll
        for (int ks = 0; ks < 4; ++ks) s = __builtin_amdgcn_mfma_f32_32x32x16_bf16(ka[ks], q0f[ks], s, 0, 0, 0);
        #pragma unroll
        for (int r = 0; r < 16; ++r) zAA[r] += __builtin_amdgcn_exp2f(s[r]);
        s = (f32x16){};
        #pragma unroll
        for (int ks = 0; ks < 4; ++ks) s = __builtin_amdgcn_mfma_f32_32x32x16_bf16(ka[ks], q1f[ks], s, 0, 0, 0);
        #pragma unroll
        for (int r = 0; r < 16; ++r) zAB[r] += __builtin_amdgcn_exp2f(s[r]);
        s = (f32x16){};
        #pragma unroll
        for (int ks = 0; ks < 4; ++ks) s = __builtin_amdgcn_mfma_f32_32x32x16_bf16(kb[ks], q0f[ks], s, 0, 0, 0);
        #pragma unroll
        for (int r = 0; r < 16; ++r) zBA[r] += __builtin_amdgcn_exp2f(s[r]);
        s = (f32x16){};
        #pragma unroll
        for (int ks = 0; ks < 4; ++ks) s = __builtin_amdgcn_mfma_f32_32x32x16_bf16(kb[ks], q1f[ks], s, 0, 0, 0);
        #pragma unroll
        for (int r = 0; r < 16; ++r) zBB[r] += __builtin_amdgcn_exp2f(s[r]);
    }

    // mask fast-path: AND-reduce rows q0..q0+63 x cols k0A..k0A+63 (int4).
    const size_t mb = (size_t)b * S_ * S_;
    int ok = 1;
    #pragma unroll
    for (int r = 0; r < 16; ++r) {
        const int4 mm = *(const int4*)&M[mb + (size_t)(q0 + 4 * r + (lane >> 4)) * S_
                                         + k0A + (lane & 15) * 4];
        ok &= (mm.x != 0) & (mm.y != 0) & (mm.z != 0) & (mm.w != 0);
    }

    float vAA[16], vAB[16], vBA[16], vBB[16];
    #pragma unroll
    for (int r = 0; r < 16; ++r) {
        vAA[r] = __builtin_amdgcn_rcpf(zAA[r]);
        vAB[r] = __builtin_amdgcn_rcpf(zAB[r]);
        vBA[r] = __builtin_amdgcn_rcpf(zBA[r]);
        vBB[r] = __builtin_amdgcn_rcpf(zBB[r]);
    }

    if (!__all(ok)) {
        // rare slow path: per-element mask (scattered; correctness only).
        // mask==0: ref softmax over all-(-inf) heads -> NaN weights.
        #pragma unroll
        for (int r = 0; r < 16; ++r) {
            const int kap = (r & 3) + 8 * (r >> 2) + 4 * hi;
            const size_t rowA = mb + (size_t)(q0 + lo) * S_;
            const size_t rowB = mb + (size_t)(q0 + 32 + lo) * S_;
            if (M[rowA + k0A + kap] == 0)      vAA[r] = __builtin_nanf("");
            if (M[rowB + k0A + kap] == 0)      vAB[r] = __builtin_nanf("");
            if (M[rowA + k0A + 32 + kap] == 0) vBA[r] = __builtin_nanf("");
            if (M[rowB + k0A + 32 + kap] == 0) vBB[r] = __builtin_nanf("");
        }
    }

    auto store_tile = [&](const float (&v)[16], int kt_, int qt_) {
        float* Zt = Zr + (((size_t)b * NT + kt_) * NT + qt_) * 1024 + (size_t)lane * 4;
        #pragma unroll
        for (int c = 0; c < 4; ++c)
            *(float4*)(Zt + c * 256) = make_float4(v[4*c], v[4*c+1], v[4*c+2], v[4*c+3]);
    };
    store_tile(vAA, ktA,     qt0);
    store_tile(vAB, ktA,     qt0 + 1);
    store_tile(vBA, ktA + 1, qt0);
    store_tile(vBB, ktA + 1, qt0 + 1);
}

// ---------------------------------------------------------------------------
// Pass 2 (R9 structure + K prefetch): out[b,n,q,:] = sum_k (exp2(s)*zr) V[k,:].
// Block = 256 thr = 4 waves, ONE (q-tile, head, b) per block; wave w sweeps
// k-tiles [w*16, w*16+16). kf double-buffered across iterations; per-iter
// issue order zr -> vf -> kf_next. Swapped QK^T; cvt_pk+permlane PV A-frags.
// Grid (qt, n, b). End: chunked 2x16-row combine (16KB obuf, 0 conflicts).
// ---------------------------------------------------------------------------
__global__ __launch_bounds__(256, 3) void pass2_av_kernel(
    const __bf16* __restrict__ QP, const __bf16* __restrict__ KP,
    const __bf16* __restrict__ VP, const float* __restrict__ Zr,
    float* __restrict__ O)
{
    __shared__ __align__(16) float obuf[4][16 * D_];    // 16 KB, end combine

    const int tid  = threadIdx.x;
    const int wv   = tid >> 6;
    const int lane = tid & 63;
    const int lo   = lane & 31;
    const int hi   = lane >> 5;

    const int qt = blockIdx.x;
    const int n  = blockIdx.y;
    const int b  = blockIdx.z;
    const int q0 = qt * TQ;

    const __bf16* Qh = QP + (((size_t)b * N_ + n) * NT + qt) * 2048 + (size_t)lane * 8;
    const __bf16* Kw = KP + (((size_t)b * N_ + n) * NT + wv * 16) * 2048 + (size_t)lane * 8;
    const __bf16* Vw = VP + (((size_t)b * N_ + n) * NT + wv * 16) * 2048 + (size_t)lane * 8;
    const float*  Zw = Zr + ((size_t)b * NT * NT + (size_t)(wv * 16) * NT + qt) * 1024
                          + (size_t)lane * 4;

    // Q fragments (pre-scaled). B-operand of the swapped QK^T.
    bf16x8 qf[4];
    #pragma unroll
    for (int ks = 0; ks < 4; ++ks)
        qf[ks] = *(const bf16x8*)(Qh + ks * 512);

    f32x16 o0 = {};  // out cols d =  0..31 (C layout)
    f32x16 o1 = {};  // out cols d = 32..63

    // prologue: first tile's K frags
    bf16x8 kf[2][4];
    #pragma unroll
    for (int ks = 0; ks < 4; ++ks)
        kf[0][ks] = *(const bf16x8*)(Kw + ks * 512);

    #pragma unroll
    for (int t = 0; t < 16; ++t) {
        const __bf16* Vt = Vw + (size_t)t * 2048;
        const float*  Zt = Zw + (size_t)t * (NT * 1024);

        // zr: 4 coalesced b128 (issued first -> usable at vmcnt(8))
        float4 z0 = *(const float4*)(Zt);
        float4 z1 = *(const float4*)(Zt + 256);
        float4 z2 = *(const float4*)(Zt + 512);
        float4 z3 = *(const float4*)(Zt + 768);
        float zr[16] = { z0.x, z0.y, z0.z, z0.w,  z1.x, z1.y, z1.z, z1.w,
                         z2.x, z2.y, z2.z, z2.w,  z3.x, z3.y, z3.z, z3.w };

        // V frags for this tile (consumed last -> longest natural cover)
        bf16x8 vf[2][2];
        #pragma unroll
        for (int kstep = 0; kstep < 2; ++kstep)
            #pragma unroll
            for (int dt = 0; dt < 2; ++dt)
                vf[kstep][dt] = *(const bf16x8*)(Vt + (kstep * 2 + dt) * 512);

        // prefetch NEXT tile's K frags (consumed next iteration)
        if (t + 1 < 16) {
            const __bf16* Kn = Kw + (size_t)(t + 1) * 2048;
            #pragma unroll
            for (int ks = 0; ks < 4; ++ks)
                kf[(t + 1) & 1][ks] = *(const bf16x8*)(Kn + ks * 512);
        }

        // swapped QK^T from registers (kf[t&1] arrived during previous iter):
        // S^T[key=row][q=lo]; lane (lo,hi) holds scores of q = q0+lo at
        // keys kap(r,hi) = (r&3)+8*(r>>2)+4*hi (+ (wv*16+t)*32)
        f32x16 s = {};
        #pragma unroll
        for (int ks = 0; ks < 4; ++ks)
            s = __builtin_amdgcn_mfma_f32_32x32x16_bf16(kf[t & 1][ks], qf[ks], s, 0, 0, 0);

        // w = exp2(s) * zr  (single v_exp_f32; NaN propagates for mask==0)
        float w[16];
        #pragma unroll
        for (int r = 0; r < 16; ++r) w[r] = __builtin_amdgcn_exp2f(s[r]) * zr[r];

        // pack to bf16 + cross-half redistribute -> exact PV A-fragments.
        #pragma unroll
        for (int kstep = 0; kstep < 2; ++kstep) {
            const int e = kstep * 8;
            unsigned int d0 = cvt_pk_bf16(w[e + 0], w[e + 1]);
            unsigned int d1 = cvt_pk_bf16(w[e + 2], w[e + 3]);
            unsigned int d2 = cvt_pk_bf16(w[e + 4], w[e + 5]);
            unsigned int d3 = cvt_pk_bf16(w[e + 6], w[e + 7]);
            permlane_swap(d0, d2);
            permlane_swap(d1, d3);
            uint32x4 u; u[0] = d0; u[1] = d1; u[2] = d2; u[3] = d3;
            const bf16x8 pa = __builtin_bit_cast(bf16x8, u);
            o0 = __builtin_amdgcn_mfma_f32_32x32x16_bf16(pa, vf[kstep][0], o0, 0, 0, 0);
            o1 = __builtin_amdgcn_mfma_f32_32x32x16_bf16(pa, vf[kstep][1], o1, 0, 0, 0);
        }
    }

    // k-split combine, chunked 2 x 16 rows (obuf 16KB, e0=tid*4: 0 conflicts).
    #pragma unroll
    for (int half = 0; half < 2; ++half) {
        if (half) __syncthreads();   // protect obuf reuse
        #pragma unroll
        for (int r8 = 0; r8 < 8; ++r8) {
            const int r  = half * 8 + r8;
            const int lr = (r8 & 3) + 8 * (r8 >> 2) + 4 * hi;  // row - 16*half
            obuf[wv][lr * D_ + lo]      = o0[r];
            obuf[wv][lr * D_ + 32 + lo] = o1[r];
        }
        __syncthreads();
        const int e0 = tid * 4;          // 1024 f32 per half / 256 thr
        float a0 = 0.f, a1 = 0.f, a2 = 0.f, a3 = 0.f;
        #pragma unroll
        for (int w = 0; w < 4; ++w) {
            const float4 x = *(const float4*)&obuf[w][e0];
            a0 += x.x; a1 += x.y; a2 += x.z; a3 += x.w;
        }
        const int q = half * 16 + (e0 >> 6);
        const int d = e0 & 63;
        *(float4*)&O[(((size_t)b * N_ + n) * S_ + q0 + q) * (size_t)D_ + d]
            = make_float4(a0, a1, a2, a3);
    }
}

// ---------------------------------------------------------------------------
// Fallback (fp32 inputs): used only if ws is too small.
// ---------------------------------------------------------------------------
__global__ __launch_bounds__(1024) void sdpa_headsm_kernel(
    const float* __restrict__ Q, const float* __restrict__ K,
    const float* __restrict__ V, const int* __restrict__ M,
    float* __restrict__ O)
{
    __shared__ __align__(16) __bf16 pbuf[N_][TQ][40];

    const int tid  = threadIdx.x;
    const int n    = tid >> 6;
    const int lane = tid & 63;
    const int lo   = lane & 31;
    const int hi   = lane >> 5;

    const int q0 = blockIdx.x * TQ;
    const int b  = blockIdx.y;
    const int kz = blockIdx.z;
    const int FITERS = S_ / TK / 4;

    bf16x8 qf[4];
    {
        const float* qrow = Q + (((size_t)b * S_ + (size_t)(q0 + lo)) * N_ + n) * D_;
        #pragma unroll
        for (int ks = 0; ks < 4; ++ks) {
            const float* p = qrow + ks * 16 + hi * 8;
            float4 a0 = *(const float4*)(p);
            float4 a1 = *(const float4*)(p + 4);
            bf16x8 f;
            f[0] = (__bf16)a0.x; f[1] = (__bf16)a0.y;
            f[2] = (__bf16)a0.z; f[3] = (__bf16)a0.w;
            f[4] = (__bf16)a1.x; f[5] = (__bf16)a1.y;
            f[6] = (__bf16)a1.z; f[7] = (__bf16)a1.w;
            qf[ks] = f;
        }
    }

    f32x16 o0 = {};
    f32x16 o1 = {};

    for (int it = 0; it < FITERS; ++it) {
        const int k0 = (kz * FITERS + it) * TK;

        f32x16 s = {};
        #pragma unroll
        for (int ks = 0; ks < 4; ++ks) {
            const float* krow = K + (((size_t)b * S_ + (size_t)(k0 + lo)) * N_ + n) * D_
                                  + ks * 16 + hi * 8;
            float4 a0 = *(const float4*)(krow);
            float4 a1 = *(const float4*)(krow + 4);
            bf16x8 f;
            f[0] = (__bf16)a0.x; f[1] = (__bf16)a0.y;
            f[2] = (__bf16)a0.z; f[3] = (__bf16)a0.w;
            f[4] = (__bf16)a1.x; f[5] = (__bf16)a1.y;
            f[6] = (__bf16)a1.z; f[7] = (__bf16)a1.w;
            s = __builtin_amdgcn_mfma_f32_32x32x16_bf16(qf[ks], f, s, 0, 0, 0);
        }

        bf16x8 vf[2][2];
        #pragma unroll
        for (int kstep = 0; kstep < 2; ++kstep) {
            #pragma unroll
            for (int dt = 0; dt < 2; ++dt) {
                bf16x8 f;
                #pragma unroll
                for (int j = 0; j < 8; ++j) {
                    const int key = k0 + kstep * 16 + hi * 8 + j;
                    f[j] = (__bf16)V[(((size_t)b * S_ + key) * N_ + n) * D_ + dt * 32 + lo];
                }
                vf[kstep][dt] = f;
            }
        }

        #pragma unroll
        for (int r = 0; r < 16; ++r) {
            const int row = (r & 3) + 8 * (r >> 2) + 4 * hi;
            pbuf[n][row][lo] = (__bf16)__builtin_amdgcn_exp2f(s[r] * QSCALE);
        }

        __syncthreads();

        {
            const int tq = tid >> 5;
            const int tk = tid & 31;
            const int m = M[(size_t)b * S_ * S_ + (size_t)(q0 + tq) * S_ + (k0 + tk)];
            float pv[16];
            float sum = 0.f;
            #pragma unroll
            for (int j = 0; j < 16; ++j) { pv[j] = (float)pbuf[j][tq][tk]; sum += pv[j]; }
            const float rd = m ? (1.0f / sum) : __builtin_nanf("");
            #pragma unroll
            for (int j = 0; j < 16; ++j) pbuf[j][tq][tk] = (__bf16)(pv[j] * rd);
        }

        __syncthreads();

        #pragma unroll
        for (int kstep = 0; kstep < 2; ++kstep) {
            bf16x8 wf = *(const bf16x8*)&pbuf[n][lo][kstep * 16 + hi * 8];
            o0 = __builtin_amdgcn_mfma_f32_32x32x16_bf16(wf, vf[kstep][0], o0, 0, 0, 0);
            o1 = __builtin_amdgcn_mfma_f32_32x32x16_bf16(wf, vf[kstep][1], o1, 0, 0, 0);
        }

        __syncthreads();
    }

    #pragma unroll
    for (int r = 0; r < 16; ++r) {
        const int row = (r & 3) + 8 * (r >> 2) + 4 * hi;
        const size_t base = (((size_t)b * N_ + n) * S_ + (q0 + row)) * (size_t)D_;
        atomicAdd(&O[base + lo],      o0[r]);
        atomicAdd(&O[base + 32 + lo], o1[r]);
    }
}

extern "C" void kernel_launch(void* const* d_in, const int* in_sizes, int n_in,
                              void* d_out, int out_size, void* d_ws, size_t ws_size,
                              hipStream_t stream) {
    const float* Q = (const float*)d_in[0];
    const float* K = (const float*)d_in[1];
    const float* V = (const float*)d_in[2];
    const int*   M = (const int*)d_in[3];
    float* O = (float*)d_out;

    const size_t per  = (size_t)B_ * N_ * NT * 2048;       // 4,194,304 elements
    const size_t zcnt = (size_t)B_ * NT * NT * 1024;       // 8,388,608 elements
    const size_t need = 3 * per * sizeof(__bf16) + zcnt * sizeof(float);  // 56 MB

    if (ws_size >= need) {
        __bf16* QP = (__bf16*)d_ws;
        __bf16* KP = QP + per;
        __bf16* VP = KP + per;
        float*  Zr = (float*)(VP + per);
        cvt_pack_kernel<<<dim3(NT, N_, 3 * B_), dim3(256), 0, stream>>>(Q, K, V, QP, KP, VP);
        pass1_z_kernel<<<dim3(NT / 8, NT / 2, B_), dim3(256), 0, stream>>>(QP, KP, M, Zr);
        pass2_av_kernel<<<dim3(NT, N_, B_), dim3(256), 0, stream>>>(QP, KP, VP, Zr, O);
    } else {
        hipMemsetAsync(d_out, 0, (size_t)out_size * sizeof(float), stream);
        sdpa_headsm_kernel<<<dim3(S_ / TQ, B_, 4), dim3(1024), 0, stream>>>(Q, K, V, M, O);
    }
}